// Round 14
// baseline (143.856 us; speedup 1.0000x reference)
//
#include <hip/hip_runtime.h>

#define BS 16
#define V  2048
#define C  512
#define PN 512
#define K  16
#define NT 256

typedef unsigned long long u64;
typedef unsigned int u32;

// --- wave64 min over u32, VALU-only (v_min_u32 + DPP), result uniform ---
template<int CTRL>
__device__ __forceinline__ u32 min_dpp_u32(u32 x) {
    const u32 n = (u32)__builtin_amdgcn_update_dpp((int)x, (int)x, CTRL, 0xF, 0xF, false);
    return n < x ? n : x;   // bound_ctrl=false: edge lanes keep own value; min idempotent
}
__device__ __forceinline__ u32 wave_min_u32(u32 x) {
    x = min_dpp_u32<0x111>(x);  // row_shr:1
    x = min_dpp_u32<0x112>(x);  // row_shr:2
    x = min_dpp_u32<0x114>(x);  // row_shr:4
    x = min_dpp_u32<0x118>(x);  // row_shr:8
    x = min_dpp_u32<0x142>(x);  // row_bcast:15
    x = min_dpp_u32<0x143>(x);  // row_bcast:31 -> lane63 = wave min
    return (u32)__builtin_amdgcn_readlane((int)x, 63);
}

__global__ __launch_bounds__(NT) void pool_knn_kernel(
    const float* __restrict__ vert,   // [BS, V, 3]
    const float* __restrict__ feat,   // [BS, V, C]
    const int*   __restrict__ sidx,   // [PN]
    float* __restrict__ out)          // [BS*PN*3] ++ [BS*PN*C]
{
    // 4 queries/block, one per WAVE (wave sees all 2048 points, 32/lane).
    // 2048 blocks; XCD swizzle (bijective, 2048%8==0): each XCD gets a
    // contiguous 256-block chunk = 2 batches -> 8MB feat working set in L2.
    const int wk = ((blockIdx.x & 7) << 8) | (blockIdx.x >> 3);
    const int b  = wk >> 7;                 // 128 blocks per batch
    const int wid = threadIdx.x >> 6;
    const int lane = threadIdx.x & 63;
    const int s = ((wk & 127) << 2) + wid;  // this wave's query slot

    __shared__ int nbr[4][K];               // per-wave winners (256 B)

    const int q = sidx[s];
    const float* vb = vert + (size_t)b * (V * 3);
    const float qx = vb[q * 3 + 0];
    const float qy = vb[q * 3 + 1];
    const float qz = vb[q * 3 + 2];
    const float qq = qx * qx + qy * qy + qz * qz;

    // ---- Phase 1: stream 32 points/lane; per-lane running top-4 (u64 lex
    //      keys (dist,idx)) via branchless 4-level cascade; e = min evicted
    //      (exact 5th-smallest seen by this lane). ----
    u64 s0 = ~0ULL, s1 = ~0ULL, s2 = ~0ULL, s3 = ~0ULL, e = ~0ULL;
    #pragma unroll 4
    for (int i = 0; i < 32; ++i) {
        const int m = i * 64 + lane;
        const float px = vb[m * 3 + 0];
        const float py = vb[m * 3 + 1];
        const float pz = vb[m * 3 + 2];
        const float pq = px * px + py * py + pz * pz;
        const float inner = qx * px + qy * py + qz * pz;
        const float dist = (-2.0f * inner + pq) + qq;   // exact ref ordering
        u32 u = __float_as_uint(dist);
        u ^= (u & 0x80000000u) ? 0xFFFFFFFFu : 0x80000000u;  // monotone map
        if (m == q) u = 0xFFFFFFFFu;                          // exclude self
        u64 x = ((u64)u << 32) | (u32)m;                      // unique lex key
        { const bool p = x < s0; const u64 mn = p ? x : s0, mx = p ? s0 : x; s0 = mn; x = mx; }
        { const bool p = x < s1; const u64 mn = p ? x : s1, mx = p ? s1 : x; s1 = mn; x = mx; }
        { const bool p = x < s2; const u64 mn = p ? x : s2, mx = p ? s2 : x; s2 = mn; x = mx; }
        { const bool p = x < s3; const u64 mn = p ? x : s3, mx = p ? s3 : x; s3 = mn; x = mx; }
        e = (x < e) ? x : e;                                  // evicted min
    }

    // ---- Phase 2: 16 pops of the wave's lex-min frontier. Frontier = s0
    //      (lists sorted); cnt==1 fast path exact (all deeper elements of
    //      other lanes exceed their frontiers). Last pop also broadcasts the
    //      winner key (B16) for validation. ----
    u64 B16 = 0;
    #pragma unroll
    for (int r = 0; r < K; ++r) {
        const u32 hi = (u32)(s0 >> 32);
        const u32 wm = wave_min_u32(hi);
        const bool pred = (hi == wm);
        const u64 mask = __ballot(pred);
        bool w_;
        if (r == K - 1) {
            const u32 widx = wave_min_u32(pred ? (u32)s0 : 0xFFFFFFFFu);
            w_ = pred && ((u32)s0 == widx);
            B16 = ((u64)wm << 32) | widx;
        } else if (__popcll(mask) == 1) {
            w_ = pred;
        } else {   // dist tie across lanes: smallest idx wins (lex-exact)
            const u32 wi = wave_min_u32(pred ? (u32)s0 : 0xFFFFFFFFu);
            w_ = pred && ((u32)s0 == wi);
        }
        if (w_) nbr[wid][r] = (int)(u32)s0;
        s0 = w_ ? s1 : s0; s1 = w_ ? s2 : s1; s2 = w_ ? s3 : s2;
        s3 = w_ ? ~0ULL : s3;
    }

    // ---- Validation: exact unless some lane evicted a key < B16 (lane held
    //      >=5 of the top-16; P ~ 2e-7 per wave). Cold fallback: exact
    //      16-round rescan with recomputed keys (keys unique -> strict >). ----
    if (__any((int)(e < B16))) {
        u64 prev = 0;
        for (int r = 0; r < K; ++r) {
            u64 best = ~0ULL;
            for (int i = 0; i < 32; ++i) {
                const int m = i * 64 + lane;
                const float px = vb[m * 3 + 0];
                const float py = vb[m * 3 + 1];
                const float pz = vb[m * 3 + 2];
                const float pq = px * px + py * py + pz * pz;
                const float inner = qx * px + qy * py + qz * pz;
                const float dist = (-2.0f * inner + pq) + qq;
                u32 u = __float_as_uint(dist);
                u ^= (u & 0x80000000u) ? 0xFFFFFFFFu : 0x80000000u;
                if (m == q) u = 0xFFFFFFFFu;
                const u64 key = ((u64)u << 32) | (u32)m;
                const bool ok = (r == 0) || (key > prev);
                const u64 cand = ok ? key : ~0ULL;
                best = (cand < best) ? cand : best;
            }
            const u32 bh  = (u32)(best >> 32);
            const u32 wmh = wave_min_u32(bh);
            const u32 wml = wave_min_u32((bh == wmh) ? (u32)best : 0xFFFFFFFFu);
            if (lane == 0) nbr[wid][r] = (int)wml;
            prev = ((u64)wmh << 32) | wml;
        }
    }

    // ---- Phase 3: gather 16 rows for THIS wave's query. Two contiguous
    //      1KB float4 loads per row (lane covers ch lane*4 and 256+lane*4). ----
    const float* fb = feat + (size_t)b * (V * C);
    const int c0 = lane * 4, c1 = 256 + lane * 4;
    float4 a0 = make_float4(-__builtin_inff(), -__builtin_inff(),
                            -__builtin_inff(), -__builtin_inff());
    float4 a1 = a0;
    #pragma unroll 4
    for (int r = 0; r < K; ++r) {
        const int idx = __builtin_amdgcn_readfirstlane(nbr[wid][r]);
        const float4 f0 = *reinterpret_cast<const float4*>(fb + (size_t)idx * C + c0);
        const float4 f1 = *reinterpret_cast<const float4*>(fb + (size_t)idx * C + c1);
        a0.x = fmaxf(a0.x, f0.x); a0.y = fmaxf(a0.y, f0.y);
        a0.z = fmaxf(a0.z, f0.z); a0.w = fmaxf(a0.w, f0.w);
        a1.x = fmaxf(a1.x, f1.x); a1.y = fmaxf(a1.y, f1.y);
        a1.z = fmaxf(a1.z, f1.z); a1.w = fmaxf(a1.w, f1.w);
    }
    float* o = out + (size_t)BS * PN * 3 + (size_t)(b * PN + s) * C;
    *reinterpret_cast<float4*>(o + c0) = a0;
    *reinterpret_cast<float4*>(o + c1) = a1;

    if (lane < 3) {
        out[(size_t)(b * PN + s) * 3 + lane] = vb[q * 3 + lane];
    }
}

extern "C" void kernel_launch(void* const* d_in, const int* in_sizes, int n_in,
                              void* d_out, int out_size, void* d_ws, size_t ws_size,
                              hipStream_t stream) {
    const float* vert = (const float*)d_in[0];
    const float* feat = (const float*)d_in[1];
    const int*   sidx = (const int*)d_in[2];
    float* out = (float*)d_out;

    pool_knn_kernel<<<(BS * PN) / 4, NT, 0, stream>>>(vert, feat, sidx, out);
}